// Round 8
// baseline (449.553 us; speedup 1.0000x reference)
//
#include <hip/hip_runtime.h>
#include <hip/hip_bf16.h>
#include <stdint.h>
#include <stddef.h>

// Problem constants
#define B_   2
#define L_   2048
#define E_   2048
#define H_   16
#define D_   128
#define F_   2048          // QKV_FEATURES
#define NROW (B_*L_)       // 4096
#define QS   6144          // fused qkv row stride (3*F_)

typedef __bf16 bf16_t;
typedef __bf16 bf16x4 __attribute__((ext_vector_type(4)));
typedef __bf16 bf16x8 __attribute__((ext_vector_type(8)));
typedef float  f32x4  __attribute__((ext_vector_type(4)));

// async global->LDS, 16B per lane. LDS dest = wave-uniform base + lane*16.
__device__ __forceinline__ void gload16(const void* g, void* l) {
  __builtin_amdgcn_global_load_lds(
      (const __attribute__((address_space(1))) void*)g,
      (__attribute__((address_space(3))) void*)l, 16, 0, 0);
}

#define VMC(n)  asm volatile("s_waitcnt vmcnt(" #n ")" ::: "memory")
#define BAR_MID do { asm volatile("" ::: "memory"); __builtin_amdgcn_s_barrier(); \
  asm volatile("s_waitcnt lgkmcnt(0)" ::: "memory"); __builtin_amdgcn_sched_barrier(0); } while(0)
#define BAR_END do { asm volatile("" ::: "memory"); __builtin_amdgcn_s_barrier(); } while(0)

// ---------------- fused prep: x->bf16 | 4x W transpose+convert | sincos table ----------------
__global__ __launch_bounds__(256) void k_prep(const float* __restrict__ x,
                                              const float* __restrict__ Wq,
                                              const float* __restrict__ Wk,
                                              const float* __restrict__ Wv,
                                              const float* __restrict__ Wo,
                                              bf16_t* __restrict__ xb,
                                              bf16_t* __restrict__ wqkvt,
                                              bf16_t* __restrict__ wot,
                                              float2* __restrict__ sc) {
  const int bb = blockIdx.x;
  if (bb < 8192) {                       // convert x (NROW*E_/4 = 2M float4 groups)
    int i = bb*256 + threadIdx.x;
    float4 v = ((const float4*)x)[i];
    bf16x4 t;
    t[0] = (__bf16)v.x; t[1] = (__bf16)v.y; t[2] = (__bf16)v.z; t[3] = (__bf16)v.w;
    ((bf16x4*)xb)[i] = t;
  } else if (bb < 24576) {               // weight transposes (64x64 tiles x 4 mats)
    __shared__ float tile[32][33];
    const int r4 = bb - 8192;
    const int z  = r4 >> 12;
    const int xy = r4 & 4095;
    const int ct = xy & 63, rt = xy >> 6;
    const float* in = (z == 0) ? Wq : (z == 1) ? Wk : (z == 2) ? Wv : Wo;
    bf16_t* out = (z < 3) ? wqkvt + (size_t)z*F_*E_ : wot;
    const int c = threadIdx.x & 31, r0 = threadIdx.x >> 5;
    #pragma unroll
    for (int k = 0; k < 4; k++) {
      int r = r0 + k*8;
      tile[r][c] = in[(size_t)(rt*32 + r)*2048 + ct*32 + c];
    }
    __syncthreads();
    #pragma unroll
    for (int k = 0; k < 4; k++) {
      int r = r0 + k*8;
      out[(size_t)(ct*32 + r)*2048 + rt*32 + c] = (__bf16)tile[c][r];
    }
  } else {                               // sincos table (L_*64 entries)
    int id = (bb - 24576)*256 + threadIdx.x;
    int t = id >> 6, i = id & 63;
    float freq = powf(10000.0f, -(float)i / 64.0f);
    float a = (float)t * freq;
    sc[id] = make_float2(cosf(a), sinf(a));
  }
}

// -------- transpose V: qkv v-slice [B*L][QS] bf16 -> Vt [B][H][D][L] bf16 --------
__global__ __launch_bounds__(256) void k_vt(const bf16_t* __restrict__ qkv,
                                            bf16_t* __restrict__ vt) {
  __shared__ bf16_t tile[32][33];
  const int bb = blockIdx.x;
  const int lt = bb & 63, dt = (bb >> 6) & 3, bh = bb >> 8;
  const int b = bh >> 4, h = bh & 15;
  const int c = threadIdx.x & 31, r0 = threadIdx.x >> 5;
  #pragma unroll
  for (int k = 0; k < 4; k++) {
    int r = r0 + k*8;
    tile[r][c] = qkv[(size_t)(b*L_ + lt*32 + r)*QS + 2*F_ + h*D_ + dt*32 + c];
  }
  __syncthreads();
  #pragma unroll
  for (int k = 0; k < 4; k++) {
    int r = r0 + k*8;
    vt[(size_t)(bh*D_ + dt*32 + r)*L_ + lt*32 + c] = tile[c][r];
  }
}

// ======== 256x256 4-phase counted-vmcnt GEMM (r6 structure, proven 787 TF) ========
// C[M][N] = A[M][K] x BT[N][K], bf16, fp32 accum. BK=64, 512 thr (8 waves 2Mx4N).
// LDS 128KB: A buf b half h at b*32768+h*16384; B same at +65536. Tile u -> buf u&1.
// Reads: ph1 A(m0-3)+B(n0-1); ph2 B(n2-3); ph3 A(m4-7). Stages: ph1 A1(u+1)->buf^1;
// ph3 B0,B1(u+2)->buf; ph4 A0(u+2)->buf. vmcnt(6) at ph4 drains tile u+1 exactly.
// MODE 1: bf16 out + fused RoPE on q/k thirds (pair = adjacent lanes, shfl_xor 1).
// MODE 2: f32 out + bias.
// Column-band XCD map: XCD x owns bx in [x*band,(x+1)*band) -> B panels L2-hot.
#define RDA03(BASE) do { _Pragma("unroll") for (int m_=0;m_<4;m_++) { \
  a[m_][0] = *(const bf16x8*)((BASE) + m_*2048 + cs0); \
  a[m_][1] = *(const bf16x8*)((BASE) + m_*2048 + cs1); } } while(0)
#define RDA47(BASE) do { _Pragma("unroll") for (int m_=0;m_<4;m_++) { \
  a[m_][0] = *(const bf16x8*)((BASE) + (m_+4)*2048 + cs0); \
  a[m_][1] = *(const bf16x8*)((BASE) + (m_+4)*2048 + cs1); } } while(0)
#define RDB01(BASE) do { _Pragma("unroll") for (int n_=0;n_<2;n_++) { \
  b[n_][0] = *(const bf16x8*)((BASE) + n_*2048 + cs0); \
  b[n_][1] = *(const bf16x8*)((BASE) + n_*2048 + cs1); } } while(0)
#define RDB23(BASE) do { _Pragma("unroll") for (int n_=0;n_<2;n_++) { \
  b[2+n_][0] = *(const bf16x8*)((BASE) + (2+n_)*2048 + cs0); \
  b[2+n_][1] = *(const bf16x8*)((BASE) + (2+n_)*2048 + cs1); } } while(0)
#define MM16(MB, NB) do { __builtin_amdgcn_s_setprio(1); \
  _Pragma("unroll") for (int m_=0;m_<4;m_++) { \
    _Pragma("unroll") for (int n_=0;n_<2;n_++) { \
      acc[(MB)+m_][(NB)+n_] = __builtin_amdgcn_mfma_f32_16x16x32_bf16(a[m_][0], b[(NB)+n_][0], acc[(MB)+m_][(NB)+n_], 0, 0, 0); \
      acc[(MB)+m_][(NB)+n_] = __builtin_amdgcn_mfma_f32_16x16x32_bf16(a[m_][1], b[(NB)+n_][1], acc[(MB)+m_][(NB)+n_], 0, 0, 0); } } \
  __builtin_amdgcn_s_setprio(0); } while(0)

template<typename OutT, int MODE>
__global__ __launch_bounds__(512, 1) void k_gemm256(const bf16_t* __restrict__ A,
                                                    const bf16_t* __restrict__ BT,
                                                    OutT* __restrict__ C,
                                                    const float* __restrict__ bias,
                                                    const float2* __restrict__ sc,
                                                    float qscale,
                                                    int M, int N, int K) {
  __shared__ char sm[131072];
  const int tid = threadIdx.x, lane = tid & 63, wave = tid >> 6;
  const int wr = wave >> 2, wc = wave & 3;
  const int lr = lane & 15, lg = lane >> 4;
  const int nbx = N >> 8;
  const int band = nbx >> 3;               // requires nbx % 8 == 0
  const int bid = blockIdx.x;
  const int idx = bid >> 3;
  const int bx = (bid & 7)*band + idx % band;
  const int by = idx / band;
  const int row0 = by << 8, col0 = bx << 8;
  // staging source (pre-swizzled 16B chunk so linear LDS dest lands swizzled)
  const int sr  = tid >> 3;                // 0..63
  const int sxe = ((tid & 7) ^ (sr & 7)) << 3;
  const bf16_t* Ag = A  + (size_t)(row0 + sr)*K + sxe;
  const bf16_t* Bg = BT + (size_t)(col0 + sr)*K + sxe;
  char* smA = sm;
  char* smB = sm + 65536;
  const int dst0 = wave*1024;
  auto stA = [&](int buf, int h, int kt) {
    const bf16_t* s = Ag + (size_t)(h*128)*K + kt;
    char* d = smA + buf*32768 + h*16384 + dst0;
    gload16(s, d); gload16(s + (size_t)64*K, d + 8192);
  };
  auto stB = [&](int buf, int h, int kt) {
    const bf16_t* s = Bg + (size_t)(h*128)*K + kt;
    char* d = smB + buf*32768 + h*16384 + dst0;
    gload16(s, d); gload16(s + (size_t)64*K, d + 8192);
  };
  // frag reads: row r at row*128 + ((ks*4+lg)^(r&7))*16; r&7 == lr&7
  const int cs0 = (lg ^ (lr & 7)) << 4;
  const int cs1 = ((4 + lg) ^ (lr & 7)) << 4;

  f32x4 acc[8][4] = {};
  bf16x8 a[4][2], b[4][2];

  // prologue: tile0 all 4 halves; tile1 A0,B0,B1 (A1(1) staged at ph1 of group 0)
  stA(0,0,0); stA(0,1,0); stB(0,0,0); stB(0,1,0);
  stA(1,0,64); stB(1,0,64); stB(1,1,64);
  VMC(6);                      // tile0 landed; A0,B0,B1(1) in flight
  BAR_END;

  const int nt = K >> 6;
  for (int u = 0; u < nt; u++) {
    const int buf = u & 1;
    const char* Ab = smA + buf*32768 + wr*16384 + lr*128;
    const char* Bb = smB + buf*32768 + (wc >> 1)*16384 + ((wc & 1)*64 + lr)*128;
    // ph1: read A(m0-3)+B(n0-1); stage A1(u+1) into buf^1
    RDA03(Ab); RDB01(Bb);
    if (u + 1 < nt) stA(buf^1, 1, (u+1) << 6);
    BAR_MID; MM16(0,0); BAR_END;
    // ph2: read B(n2-3)
    RDB23(Bb);
    BAR_MID; MM16(0,2); BAR_END;
    // ph3: read A(m4-7); stage B halves of u+2 into buf
    RDA47(Ab);
    if (u + 2 < nt) { stB(buf, 0, (u+2) << 6); stB(buf, 1, (u+2) << 6); }
    BAR_MID; MM16(4,0); BAR_END;
    // ph4: stage A0(u+2); checkpoint drains tile u+1
    if (u + 2 < nt) {
      stA(buf, 0, (u+2) << 6);
      BAR_MID; MM16(4,2); VMC(6); BAR_END;
    } else {
      BAR_MID; MM16(4,2); VMC(0); BAR_END;
    }
  }
  // epilogue: C/D layout col=lane&15, row=(lane>>4)*4+j (m89-verified)
  #pragma unroll
  for (int m = 0; m < 8; m++) {
    #pragma unroll
    for (int n = 0; n < 4; n++) {
      const int col = col0 + wc*64 + n*16 + lr;
      if (MODE == 2) {
        const float bv = bias[col];
        #pragma unroll
        for (int j = 0; j < 4; j++) {
          const int row = row0 + wr*128 + m*16 + lg*4 + j;
          C[(size_t)row*N + col] = (OutT)(acc[m][n][j] + bv);
        }
      } else {
        // MODE 1: fused RoPE on q (third 0, pre-scaled) and k (third 1) in f32.
        const int third = col >> 11;
        const int ii    = (col & (D_-1)) >> 1;
        const bool odd  = (lr & 1);
        const float ss  = (third == 0) ? qscale : 1.0f;
        #pragma unroll
        for (int j = 0; j < 4; j++) {
          const int row = row0 + wr*128 + m*16 + lg*4 + j;
          const float v0 = acc[m][n][j];
          const float vp = __shfl_xor(v0, 1);
          float res;
          if (third == 2) {
            res = v0;
          } else {
            const int t = row & (L_-1);
            const float2 cs = sc[t*64 + ii];
            const float cosv = cs.x * ss, sinv = cs.y * ss;
            res = odd ? (vp*sinv + v0*cosv) : (v0*cosv - vp*sinv);
          }
          C[(size_t)row*N + col] = (OutT)res;
        }
      }
    }
  }
}

// -------- Flash attention tile compute (swapped-operand form, unchanged) --------
template<bool MASK>
__device__ __forceinline__ void attn_tile(
    int kv0, int wq0, int lr, int lg,
    const char* __restrict__ Kb, const char* __restrict__ Vb, char* __restrict__ Pb,
    const bf16x8 (&aq)[4], f32x4 (&o)[8], float& mrow, float& lsum) {
  const int swz = (lr & 7) << 4;
  f32x4 s[4] = {};
  #pragma unroll
  for (int kd = 0; kd < 4; kd++) {
    bf16x8 ak[4];
    #pragma unroll
    for (int n = 0; n < 4; n++)
      ak[n] = *(const bf16x8*)(Kb + (n*16 + lr)*256 + (((kd*4 + lg) << 4) ^ swz));
    __builtin_amdgcn_s_setprio(1);
    #pragma unroll
    for (int n = 0; n < 4; n++)
      s[n] = __builtin_amdgcn_mfma_f32_16x16x32_bf16(ak[n], aq[kd], s[n], 0, 0, 0);
    __builtin_amdgcn_s_setprio(0);
  }
  if (MASK) {
    const int q = wq0 + lr;
    #pragma unroll
    for (int n = 0; n < 4; n++)
      #pragma unroll
      for (int j = 0; j < 4; j++)
        if (kv0 + n*16 + lg*4 + j > q) s[n][j] = -30000.0f;
  }
  float pmax = fmaxf(
      fmaxf(fmaxf(fmaxf(s[0][0], s[0][1]), fmaxf(s[0][2], s[0][3])),
            fmaxf(fmaxf(s[1][0], s[1][1]), fmaxf(s[1][2], s[1][3]))),
      fmaxf(fmaxf(fmaxf(s[2][0], s[2][1]), fmaxf(s[2][2], s[2][3])),
            fmaxf(fmaxf(s[3][0], s[3][1]), fmaxf(s[3][2], s[3][3]))));
  pmax = fmaxf(pmax, __shfl_xor(pmax, 16));
  pmax = fmaxf(pmax, __shfl_xor(pmax, 32));
  if (!__all(pmax - mrow <= 8.0f)) {       // defer-max (T13)
    const float mnew = fmaxf(mrow, pmax);
    const float corr = exp2f(mrow - mnew);
    mrow = mnew;
    lsum *= corr;
    #pragma unroll
    for (int n2 = 0; n2 < 8; n2++) o[n2] *= corr;
  }
  float rs = 0.0f;
  #pragma unroll
  for (int n = 0; n < 4; n++)
    #pragma unroll
    for (int j = 0; j < 4; j++) {
      float p = exp2f(s[n][j] - mrow);
      s[n][j] = p;
      rs += p;
    }
  rs += __shfl_xor(rs, 16);
  rs += __shfl_xor(rs, 32);
  lsum += rs;
  #pragma unroll
  for (int n = 0; n < 4; n++) {
    bf16x4 pw;
    pw[0] = (__bf16)s[n][0]; pw[1] = (__bf16)s[n][1];
    pw[2] = (__bf16)s[n][2]; pw[3] = (__bf16)s[n][3];
    *(bf16x4*)(Pb + ((lr*128 + n*32 + lg*8) ^ swz)) = pw;
  }
  #pragma unroll
  for (int ks = 0; ks < 2; ks++) {
    bf16x8 pb = *(const bf16x8*)(Pb + ((lr*128 + ks*64 + lg*16) ^ swz));
    __builtin_amdgcn_s_setprio(1);
    #pragma unroll
    for (int n2 = 0; n2 < 8; n2++) {
      bf16x8 av = *(const bf16x8*)(Vb + (n2*16 + lr)*128 + (((ks*4 + lg) << 4) ^ swz));
      o[n2] = __builtin_amdgcn_mfma_f32_16x16x32_bf16(av, pb, o[n2], 0, 0, 0);
    }
    __builtin_amdgcn_s_setprio(0);
  }
}

// -------- Flash attention, causal. 4 waves x 16 q-rows = 64 q-rows/block. --------
// 256 threads, 72KB LDS -> target 2 blocks/CU (r4 evidence: 512-thr blocks stuck at
// 1 block/CU regardless of LDS; smaller blocks are the occupancy lever).
// Grid 1024; XCD bh-chunking (4 bh per XCD, K+V L2-hot); qt heavy-first.
__global__ __launch_bounds__(256, 2) void k_attn(const bf16_t* __restrict__ QKV,
                                                 const bf16_t* __restrict__ Vt,
                                                 bf16_t* __restrict__ O) {
  __shared__ bf16_t Ks[2][64*128];    // 16KB per buf
  __shared__ bf16_t Vs[2][128*64];    // 16KB per buf
  __shared__ bf16_t Pl[4][16*64];     // 2KB per wave
  const int tid = threadIdx.x, lane = tid & 63, wave = tid >> 6;
  const int bidx = blockIdx.x;
  const int xcd = bidx & 7, idx = bidx >> 3;       // idx 0..127
  const int bh  = xcd*4 + (idx & 3);               // 4 (b,h) pairs per XCD
  const int qt  = 31 - (idx >> 2);                 // heavy first (64-row q tiles)
  const int b = bh >> 4, h = bh & 15;
  const int wq0 = qt*64 + wave*16;
  const int lr = lane & 15, lg = lane >> 4;
  char* Pb = (char*)&Pl[wave][0];
  const bf16_t* Q = QKV;
  const bf16_t* K = QKV + F_;

  bf16x8 aq[4];
  #pragma unroll
  for (int kd = 0; kd < 4; kd++)
    aq[kd] = *(const bf16x8*)&Q[(size_t)(b*L_ + wq0 + lr)*QS + h*D_ + kd*32 + lg*8];

  // staging (256 threads, 4 instrs per 16KB region, pre-swizzled source)
  const int kr = tid >> 4, kc = tid & 15;     // K: rows i*16+kr, chunk kc of 16
  const bf16_t* Kg0 = K + (size_t)(b*L_ + kr)*QS + h*D_ + ((kc ^ (kr & 7)) << 3);
  const int vr = tid >> 3, vc = tid & 7;      // V: d-rows i*32+vr, chunk vc of 8
  const bf16_t* Vg0 = Vt + (size_t)((b*H_ + h)*D_ + vr)*L_ + ((vc ^ (vr & 7)) << 3);
  const int dst0 = wave*1024;
  auto stageKV = [&](int bufi, int kv) {
    char* kb = (char*)&Ks[bufi][0] + dst0;
    char* vb = (char*)&Vs[bufi][0] + dst0;
    const bf16_t* kg = Kg0 + (size_t)kv*QS;
    const bf16_t* vg = Vg0 + kv;
    #pragma unroll
    for (int i = 0; i < 4; i++) {
      gload16(kg + (size_t)(i*16)*QS, kb + i*4096);
      gload16(vg + (size_t)(i*32)*L_, vb + i*4096);
    }
  };

  f32x4 o[8] = {};
  float mrow = -3.0e38f, lsum = 0.0f;
  const int ntb   = qt + 1;                   // block covers kv < (qt+1)*64
  const int nfull = (wq0 + 1) >> 6;
  const int nmine = ((wq0 + 15) >> 6) + 1;

  stageKV(0, 0);
  __syncthreads();

  int buf = 0;
  for (int t = 0; t < ntb; t++) {
    if (t + 1 < ntb) stageKV(buf^1, (t+1)*64);
    const char* Kb = (const char*)&Ks[buf][0];
    const char* Vb = (const char*)&Vs[buf][0];
    if (t < nfull)
      attn_tile<false>(t*64, wq0, lr, lg, Kb, Vb, Pb, aq, o, mrow, lsum);
    else if (t < nmine)
      attn_tile<true >(t*64, wq0, lr, lg, Kb, Vb, Pb, aq, o, mrow, lsum);
    __syncthreads();                           // drains stage; all waves done with buf
    buf ^= 1;
  }
  const float inv = 1.0f / lsum;
  bf16_t* orow = O + (size_t)(b*L_ + wq0 + lr)*F_ + h*D_ + lg*4;
  #pragma unroll
  for (int n2 = 0; n2 < 8; n2++) {
    bf16x4 ov;
    ov[0] = (__bf16)(o[n2][0]*inv); ov[1] = (__bf16)(o[n2][1]*inv);
    ov[2] = (__bf16)(o[n2][2]*inv); ov[3] = (__bf16)(o[n2][3]*inv);
    *(bf16x4*)(orow + n2*16) = ov;
  }
}

extern "C" void kernel_launch(void* const* d_in, const int* in_sizes, int n_in,
                              void* d_out, int out_size, void* d_ws, size_t ws_size,
                              hipStream_t stream) {
  const float* x  = (const float*)d_in[0];
  const float* Wq = (const float*)d_in[1];
  const float* Wk = (const float*)d_in[2];
  const float* Wv = (const float*)d_in[3];
  const float* Wo = (const float*)d_in[4];
  const float* bo = (const float*)d_in[5];
  float* out = (float*)d_out;

  char* ws = (char*)d_ws;
  size_t off = 0;
  auto alloc = [&](size_t bytes) {
    char* p = ws + off;
    off = (off + bytes + 255) & ~(size_t)255;
    return p;
  };
  bf16_t* xb    = (bf16_t*)alloc((size_t)NROW*E_*2);     // x bf16; reused as attn out
  bf16_t* wqkvt = (bf16_t*)alloc((size_t)3*F_*E_*2);     // [Wq^T;Wk^T;Wv^T] bf16
  bf16_t* wot   = (bf16_t*)alloc((size_t)F_*E_*2);       // Wo^T bf16 [E][F]
  float2* sc    = (float2*)alloc((size_t)L_*64*sizeof(float2));
  bf16_t* qkv   = (bf16_t*)alloc((size_t)NROW*QS*2);     // fused QKV [4096][6144]
  bf16_t* vt    = (bf16_t*)alloc((size_t)NROW*F_*2);     // V^T [B][H][D][L]
  bf16_t* ob    = xb;                                    // attn output (xb dead by then)

  const float scale2 = 0.08838834764831845f * 1.44269504088896f;  // 1/sqrt(D)*log2(e)

  // 1. fused prep: convert + 4 weight transposes + sincos (one launch)
  k_prep<<<dim3(25088), 256, 0, stream>>>(x, Wq, Wk, Wv, Wo, xb, wqkvt, wot, sc);

  // 2. fused QKV projection + RoPE epilogue (r6 4-phase 256^2 loop)
  k_gemm256<bf16_t, 1><<<dim3((QS/256)*(NROW/256)), 512, 0, stream>>>(
      xb, wqkvt, qkv, nullptr, sc, scale2, NROW, QS, E_);

  // 3. V transpose
  k_vt<<<dim3(8192), 256, 0, stream>>>(qkv, vt);

  // 4. flash attention (1024 blocks x 256 threads, XCD bh-chunked)
  k_attn<<<dim3(1024), 256, 0, stream>>>(qkv, vt, ob);

  // 5. output projection + bias
  k_gemm256<float, 2><<<dim3((E_/256)*(NROW/256)), 512, 0, stream>>>(
      ob, wot, out, bo, nullptr, 1.0f, NROW, E_, F_);
}